// Round 1
// baseline (921.062 us; speedup 1.0000x reference)
//
#include <hip/hip_runtime.h>
#include <cstddef>

#define BB   8
#define NUU  1024
#define NII  2048
#define NTOT 3072
#define DD   64
#define EPART 1572864  // 8*3072*64

// ---------------- gather: ego0 = concat(user_table[uidx], item_table[iidx]) ----------------
__global__ __launch_bounds__(256) void gather_kernel(
    const int* __restrict__ uidx, const int* __restrict__ iidx,
    const float* __restrict__ utab, const float* __restrict__ itab,
    float* __restrict__ e0) {
  int g = blockIdx.x * 256 + threadIdx.x;     // one float4 per thread
  int c4 = g & 15;
  int r2 = g >> 4;
  int b = r2 / NTOT;
  int row = r2 - b * NTOT;
  const float* src = (row < NUU) ? (utab + (size_t)uidx[b * NUU + row] * DD)
                                 : (itab + (size_t)iidx[b * NII + row - NUU] * DD);
  float4 v = reinterpret_cast<const float4*>(src)[c4];
  reinterpret_cast<float4*>(e0 + ((size_t)b * NTOT + row) * DD)[c4] = v;
}

// ---------------- side = adj @ e_in  (fp32, 64-row tile, K split in 2) ----------------
__global__ __launch_bounds__(256) void side_gemm(
    const float* __restrict__ adj, const float* __restrict__ e_in,
    float* __restrict__ sp) {
  __shared__ float At[32][68];   // transposed adj tile, padded stride
  __shared__ float Bs[32][64];   // e tile
  const int tid = threadIdx.x;
  const int b  = blockIdx.z;
  const int kz = blockIdx.y;
  const int m0 = blockIdx.x * 64;
  const float* A = adj  + (size_t)b * NTOT * NTOT;
  const float* E = e_in + (size_t)b * NTOT * DD;
  float* S = sp + (size_t)kz * (size_t)BB * NTOT * DD + (size_t)b * NTOT * DD;
  const int ldRow = tid >> 3;          // 0..31
  const int ldK4  = (tid & 7) * 4;     // 0,4,..,28
  const int eR    = tid >> 4;          // 0..15
  const int eC    = (tid & 15) * 4;    // 0..60
  const int trow  = (tid >> 4) * 4;
  const int tcol  = (tid & 15) * 4;

  const int kbeg = kz * 1536, kend = kbeg + 1536;
  float4 pa0 = *reinterpret_cast<const float4*>(A + (size_t)(m0 + ldRow)      * NTOT + kbeg + ldK4);
  float4 pa1 = *reinterpret_cast<const float4*>(A + (size_t)(m0 + ldRow + 32) * NTOT + kbeg + ldK4);
  float4 pe0 = *reinterpret_cast<const float4*>(E + (size_t)(kbeg + eR)      * DD + eC);
  float4 pe1 = *reinterpret_cast<const float4*>(E + (size_t)(kbeg + eR + 16) * DD + eC);

  float acc[4][4] = {};

  for (int k0 = kbeg; k0 < kend; k0 += 32) {
    __syncthreads();
    At[ldK4 + 0][ldRow] = pa0.x; At[ldK4 + 1][ldRow] = pa0.y;
    At[ldK4 + 2][ldRow] = pa0.z; At[ldK4 + 3][ldRow] = pa0.w;
    At[ldK4 + 0][ldRow + 32] = pa1.x; At[ldK4 + 1][ldRow + 32] = pa1.y;
    At[ldK4 + 2][ldRow + 32] = pa1.z; At[ldK4 + 3][ldRow + 32] = pa1.w;
    *reinterpret_cast<float4*>(&Bs[eR][eC])      = pe0;
    *reinterpret_cast<float4*>(&Bs[eR + 16][eC]) = pe1;
    __syncthreads();
    if (k0 + 32 < kend) {
      pa0 = *reinterpret_cast<const float4*>(A + (size_t)(m0 + ldRow)      * NTOT + k0 + 32 + ldK4);
      pa1 = *reinterpret_cast<const float4*>(A + (size_t)(m0 + ldRow + 32) * NTOT + k0 + 32 + ldK4);
      pe0 = *reinterpret_cast<const float4*>(E + (size_t)(k0 + 32 + eR)      * DD + eC);
      pe1 = *reinterpret_cast<const float4*>(E + (size_t)(k0 + 32 + eR + 16) * DD + eC);
    }
#pragma unroll
    for (int k = 0; k < 32; k++) {
      float4 av = *reinterpret_cast<const float4*>(&At[k][trow]);
      float4 bv = *reinterpret_cast<const float4*>(&Bs[k][tcol]);
      acc[0][0] += av.x * bv.x; acc[0][1] += av.x * bv.y; acc[0][2] += av.x * bv.z; acc[0][3] += av.x * bv.w;
      acc[1][0] += av.y * bv.x; acc[1][1] += av.y * bv.y; acc[1][2] += av.y * bv.z; acc[1][3] += av.y * bv.w;
      acc[2][0] += av.z * bv.x; acc[2][1] += av.z * bv.y; acc[2][2] += av.z * bv.z; acc[2][3] += av.z * bv.w;
      acc[3][0] += av.w * bv.x; acc[3][1] += av.w * bv.y; acc[3][2] += av.w * bv.z; acc[3][3] += av.w * bv.w;
    }
  }
#pragma unroll
  for (int r = 0; r < 4; r++) {
    float4 o = make_float4(acc[r][0], acc[r][1], acc[r][2], acc[r][3]);
    *reinterpret_cast<float4*>(S + (size_t)(m0 + trow + r) * DD + tcol) = o;
  }
}

// ---------------- ego_out = lrelu(side@gcW^T+gcb) + lrelu((ego*side)@biW^T+bib) ----------------
__global__ __launch_bounds__(256) void layer_post(
    const float* __restrict__ sp, const float* __restrict__ e_in,
    const float* __restrict__ gcw, const float* __restrict__ gcb,
    const float* __restrict__ biw, const float* __restrict__ bib,
    float* __restrict__ e_out) {
  __shared__ float wG[4096];
  __shared__ float wB[4096];
  __shared__ float rowS[4][64];
  __shared__ float rowE[4][64];
  const int tid = threadIdx.x;
#pragma unroll
  for (int i = 0; i < 16; i++) {
    int idx = tid + i * 256;
    int k = idx >> 6, d = idx & 63;
    wG[idx] = gcw[d * 64 + k];   // transposed: wG[k*64+d]
    wB[idx] = biw[d * 64 + k];
  }
  const int wv = tid >> 6, lane = tid & 63;
  const size_t row = (size_t)blockIdx.x * 4 + wv;
  const size_t off = row * DD + lane;
  float sv = sp[off] + sp[(size_t)BB * NTOT * DD + off];  // sum K-split partials
  float ev = e_in[off];
  rowS[wv][lane] = sv;
  rowE[wv][lane] = ev;
  __syncthreads();
  float sacc = gcb[lane];
  float bacc = bib[lane];
#pragma unroll 8
  for (int k = 0; k < 64; k++) {
    float sk = rowS[wv][k];
    float ek = rowE[wv][k];
    sacc += sk * wG[k * 64 + lane];
    bacc += (ek * sk) * wB[k * 64 + lane];
  }
  float s  = sacc > 0.f ? sacc : 0.01f * sacc;
  float bi = bacc > 0.f ? bacc : 0.01f * bacc;
  e_out[off] = s + bi;
}

// ---------------- scores = u_g @ i_g^T over K=192 (e0|e1|e2) ----------------
__global__ __launch_bounds__(256) void scores_gemm(
    const float* __restrict__ e0, const float* __restrict__ e1,
    const float* __restrict__ e2, float* __restrict__ out) {
  __shared__ float Ut[32][68];
  __shared__ float It[32][68];
  const int tid = threadIdx.x;
  const int b  = blockIdx.z;
  const int u0 = blockIdx.y * 64;
  const int i0 = blockIdx.x * 64;
  const int ldRow = tid >> 3;
  const int ldK4  = (tid & 7) * 4;
  const int trow  = (tid >> 4) * 4;
  const int tcol  = (tid & 15) * 4;
  float acc[4][4] = {};
  const float* eps[3] = {e0, e1, e2};
#pragma unroll
  for (int t = 0; t < 6; t++) {
    const float* ep = eps[t >> 1];
    const int part = (t & 1) * 32;
    const float* Ub = ep + ((size_t)b * NTOT + u0) * DD + part;
    const float* Ib = ep + ((size_t)b * NTOT + NUU + i0) * DD + part;
    float4 a0 = *reinterpret_cast<const float4*>(Ub + (size_t)ldRow * DD + ldK4);
    float4 a1 = *reinterpret_cast<const float4*>(Ub + (size_t)(ldRow + 32) * DD + ldK4);
    float4 b0 = *reinterpret_cast<const float4*>(Ib + (size_t)ldRow * DD + ldK4);
    float4 b1 = *reinterpret_cast<const float4*>(Ib + (size_t)(ldRow + 32) * DD + ldK4);
    __syncthreads();
    Ut[ldK4 + 0][ldRow] = a0.x; Ut[ldK4 + 1][ldRow] = a0.y;
    Ut[ldK4 + 2][ldRow] = a0.z; Ut[ldK4 + 3][ldRow] = a0.w;
    Ut[ldK4 + 0][ldRow + 32] = a1.x; Ut[ldK4 + 1][ldRow + 32] = a1.y;
    Ut[ldK4 + 2][ldRow + 32] = a1.z; Ut[ldK4 + 3][ldRow + 32] = a1.w;
    It[ldK4 + 0][ldRow] = b0.x; It[ldK4 + 1][ldRow] = b0.y;
    It[ldK4 + 2][ldRow] = b0.z; It[ldK4 + 3][ldRow] = b0.w;
    It[ldK4 + 0][ldRow + 32] = b1.x; It[ldK4 + 1][ldRow + 32] = b1.y;
    It[ldK4 + 2][ldRow + 32] = b1.z; It[ldK4 + 3][ldRow + 32] = b1.w;
    __syncthreads();
#pragma unroll
    for (int k = 0; k < 32; k++) {
      float4 av = *reinterpret_cast<const float4*>(&Ut[k][trow]);
      float4 bv = *reinterpret_cast<const float4*>(&It[k][tcol]);
      acc[0][0] += av.x * bv.x; acc[0][1] += av.x * bv.y; acc[0][2] += av.x * bv.z; acc[0][3] += av.x * bv.w;
      acc[1][0] += av.y * bv.x; acc[1][1] += av.y * bv.y; acc[1][2] += av.y * bv.z; acc[1][3] += av.y * bv.w;
      acc[2][0] += av.z * bv.x; acc[2][1] += av.z * bv.y; acc[2][2] += av.z * bv.z; acc[2][3] += av.z * bv.w;
      acc[3][0] += av.w * bv.x; acc[3][1] += av.w * bv.y; acc[3][2] += av.w * bv.z; acc[3][3] += av.w * bv.w;
    }
  }
  float* O = out + ((size_t)b * NUU + u0) * NII + i0;
#pragma unroll
  for (int r = 0; r < 4; r++) {
    float4 o = make_float4(acc[r][0], acc[r][1], acc[r][2], acc[r][3]);
    *reinterpret_cast<float4*>(O + (size_t)(trow + r) * NII + tcol) = o;
  }
}

// ---------------- in-place row log_softmax over 2048 ----------------
__global__ __launch_bounds__(256) void logsoftmax_kernel(float* __restrict__ out) {
  __shared__ float rm[4];
  __shared__ float rs[4];
  const int tid = threadIdx.x;
  const int lane = tid & 63, wv = tid >> 6;
  float* row = out + (size_t)blockIdx.x * NII;
  float4 v0 = *reinterpret_cast<const float4*>(row + tid * 4);
  float4 v1 = *reinterpret_cast<const float4*>(row + 1024 + tid * 4);
  float m = fmaxf(fmaxf(fmaxf(v0.x, v0.y), fmaxf(v0.z, v0.w)),
                  fmaxf(fmaxf(v1.x, v1.y), fmaxf(v1.z, v1.w)));
#pragma unroll
  for (int off = 32; off > 0; off >>= 1) m = fmaxf(m, __shfl_xor(m, off));
  if (lane == 0) rm[wv] = m;
  __syncthreads();
  m = fmaxf(fmaxf(rm[0], rm[1]), fmaxf(rm[2], rm[3]));
  float s = expf(v0.x - m) + expf(v0.y - m) + expf(v0.z - m) + expf(v0.w - m) +
            expf(v1.x - m) + expf(v1.y - m) + expf(v1.z - m) + expf(v1.w - m);
#pragma unroll
  for (int off = 32; off > 0; off >>= 1) s += __shfl_xor(s, off);
  if (lane == 0) rs[wv] = s;
  __syncthreads();
  float lse = m + logf(rs[0] + rs[1] + rs[2] + rs[3]);
  v0.x -= lse; v0.y -= lse; v0.z -= lse; v0.w -= lse;
  v1.x -= lse; v1.y -= lse; v1.z -= lse; v1.w -= lse;
  *reinterpret_cast<float4*>(row + tid * 4) = v0;
  *reinterpret_cast<float4*>(row + 1024 + tid * 4) = v1;
}

extern "C" void kernel_launch(void* const* d_in, const int* in_sizes, int n_in,
                              void* d_out, int out_size, void* d_ws, size_t ws_size,
                              hipStream_t stream) {
  (void)in_sizes; (void)n_in; (void)out_size; (void)ws_size;
  const int*   uidx = (const int*)d_in[0];
  const int*   iidx = (const int*)d_in[1];
  const float* adj  = (const float*)d_in[2];
  const float* utab = (const float*)d_in[3];
  const float* itab = (const float*)d_in[4];
  const float* gcw  = (const float*)d_in[5];
  const float* gcb  = (const float*)d_in[6];
  const float* biw  = (const float*)d_in[7];
  const float* bib  = (const float*)d_in[8];
  float* out = (float*)d_out;
  float* e0 = (float*)d_ws;
  float* e1 = e0 + EPART;
  float* e2 = e1 + EPART;
  // side K-split partials live in d_out (3.1M floats << 16.8M); overwritten by scores later
  float* sp = out;

  gather_kernel<<<dim3(BB * NTOT * 16 / 256), 256, 0, stream>>>(uidx, iidx, utab, itab, e0);
  side_gemm<<<dim3(48, 2, BB), 256, 0, stream>>>(adj, e0, sp);
  layer_post<<<dim3(BB * NTOT / 4), 256, 0, stream>>>(sp, e0, gcw, gcb, biw, bib, e1);
  side_gemm<<<dim3(48, 2, BB), 256, 0, stream>>>(adj, e1, sp);
  layer_post<<<dim3(BB * NTOT / 4), 256, 0, stream>>>(sp, e1, gcw + 4096, gcb + 64, biw + 4096, bib + 64, e2);
  scores_gemm<<<dim3(32, 16, BB), 256, 0, stream>>>(e0, e1, e2, out);
  logsoftmax_kernel<<<dim3(BB * NUU), 256, 0, stream>>>(out);
}

// Round 2
// 840.129 us; speedup vs baseline: 1.0963x; 1.0963x over previous
//
#include <hip/hip_runtime.h>
#include <cstddef>

#define BB   8
#define NUU  1024
#define NII  2048
#define NTOT 3072
#define DD   64
#define KCAT 192

typedef __attribute__((ext_vector_type(8))) short bf16x8;
typedef __attribute__((ext_vector_type(4))) float f32x4;

__device__ __forceinline__ unsigned short f2bf(float f) {
  unsigned u = __float_as_uint(f);
  return (unsigned short)((u + 0x7fffu + ((u >> 16) & 1u)) >> 16);  // RNE
}
__device__ __forceinline__ float bf2f(unsigned short s) {
  return __uint_as_float(((unsigned)s) << 16);
}
__device__ __forceinline__ uint4 pack8(float4 a, float4 b) {
  uint4 r;
  r.x = (unsigned)f2bf(a.x) | ((unsigned)f2bf(a.y) << 16);
  r.y = (unsigned)f2bf(a.z) | ((unsigned)f2bf(a.w) << 16);
  r.z = (unsigned)f2bf(b.x) | ((unsigned)f2bf(b.y) << 16);
  r.w = (unsigned)f2bf(b.z) | ((unsigned)f2bf(b.w) << 16);
  return r;
}

// ---- gather: ecat[:, :, 0:64] = bf16(table rows); 4 threads/node ----
__global__ __launch_bounds__(256) void gather_bf16(
    const int* __restrict__ uidx, const int* __restrict__ iidx,
    const float* __restrict__ utab, const float* __restrict__ itab,
    unsigned short* __restrict__ ecat) {
  int g = blockIdx.x * 256 + threadIdx.x;
  int node_g = g >> 2;
  int f0 = (g & 3) * 16;
  int b = node_g / NTOT;
  int row = node_g - b * NTOT;
  const float* src = (row < NUU) ? utab + (size_t)uidx[b * NUU + row] * DD
                                 : itab + (size_t)iidx[b * NII + row - NUU] * DD;
  const float4* s4 = reinterpret_cast<const float4*>(src + f0);
  uint4 lo = pack8(s4[0], s4[1]);
  uint4 hi = pack8(s4[2], s4[3]);
  uint4* dst = reinterpret_cast<uint4*>(ecat + (size_t)node_g * KCAT + f0);
  dst[0] = lo; dst[1] = hi;
}

// ---- transpose ecat[:, :, c0:c0+64] -> Et[b][64][3072] (feature-major) ----
__global__ __launch_bounds__(256) void conv_t(
    const unsigned short* __restrict__ ecat, int c0,
    unsigned short* __restrict__ Et) {
  __shared__ unsigned short T[64][65];
  const int tid = threadIdx.x;
  const int b = blockIdx.y;
  const int r0 = blockIdx.x * 64;
  {
    int nl = tid >> 2, fg = (tid & 3) * 16;
    const uint4* src = reinterpret_cast<const uint4*>(
        ecat + ((size_t)b * NTOT + r0 + nl) * KCAT + c0 + fg);
    uint4 v0 = src[0], v1 = src[1];
    unsigned short tmp[16];
    *reinterpret_cast<uint4*>(tmp) = v0;
    *reinterpret_cast<uint4*>(tmp + 8) = v1;
#pragma unroll
    for (int j = 0; j < 16; j++) T[fg + j][nl] = tmp[j];
  }
  __syncthreads();
  {
    int f = tid >> 2, ng = (tid & 3) * 16;
    unsigned short tmp[16];
#pragma unroll
    for (int j = 0; j < 16; j++) tmp[j] = T[f][ng + j];
    uint4* dst = reinterpret_cast<uint4*>(
        Et + ((size_t)b * DD + f) * NTOT + r0 + ng);
    dst[0] = *reinterpret_cast<uint4*>(tmp);
    dst[1] = *reinterpret_cast<uint4*>(tmp + 8);
  }
}

// ---- side partial = adj[m,krange] @ E : MFMA 16x16x32 bf16, no LDS ----
__global__ __launch_bounds__(256) void side_mfma(
    const float* __restrict__ adj, const unsigned short* __restrict__ Et,
    float* __restrict__ sp) {
  const int tid = threadIdx.x;
  const int w = tid >> 6, l = tid & 63;
  const int lane15 = l & 15, quad = l >> 4;
  const int b = blockIdx.z, kz = blockIdx.y;
  const int m0 = blockIdx.x * 64 + w * 16;
  const float* A = adj + (size_t)b * NTOT * NTOT + (size_t)(m0 + lane15) * NTOT;
  const unsigned short* B0 =
      Et + (size_t)b * DD * NTOT + (size_t)lane15 * NTOT + kz * 768 + quad * 8;
  const float* Ak = A + kz * 768 + quad * 8;
  f32x4 acc[4];
#pragma unroll
  for (int t = 0; t < 4; t++) acc[t] = (f32x4){0.f, 0.f, 0.f, 0.f};
#pragma unroll 2
  for (int k = 0; k < 768; k += 32) {
    float4 a0 = *reinterpret_cast<const float4*>(Ak + k);
    float4 a1 = *reinterpret_cast<const float4*>(Ak + k + 4);
    union { bf16x8 v; unsigned short s[8]; } af;
    af.s[0] = f2bf(a0.x); af.s[1] = f2bf(a0.y);
    af.s[2] = f2bf(a0.z); af.s[3] = f2bf(a0.w);
    af.s[4] = f2bf(a1.x); af.s[5] = f2bf(a1.y);
    af.s[6] = f2bf(a1.z); af.s[7] = f2bf(a1.w);
#pragma unroll
    for (int t = 0; t < 4; t++) {
      bf16x8 bf = *reinterpret_cast<const bf16x8*>(B0 + (size_t)t * 16 * NTOT + k);
      acc[t] = __builtin_amdgcn_mfma_f32_16x16x32_bf16(af.v, bf, acc[t], 0, 0, 0);
    }
  }
  float* S = sp + ((size_t)kz * BB + b) * ((size_t)NTOT * DD);
#pragma unroll
  for (int t = 0; t < 4; t++)
#pragma unroll
    for (int r = 0; r < 4; r++)
      S[(size_t)(m0 + quad * 4 + r) * DD + t * 16 + lane15] = acc[t][r];
}

// ---- ego_out = lrelu(side@gcW^T+gcb) + lrelu((ego*side)@biW^T+bib), bf16 io ----
__global__ __launch_bounds__(256) void layer_post(
    const float* __restrict__ sp, unsigned short* __restrict__ ecat, int cin,
    const float* __restrict__ gcw, const float* __restrict__ gcb,
    const float* __restrict__ biw, const float* __restrict__ bib) {
  __shared__ float wG[4096];
  __shared__ float wB[4096];
  __shared__ float rowS[4][64];
  __shared__ float rowE[4][64];
  const int tid = threadIdx.x;
#pragma unroll
  for (int i = 0; i < 16; i++) {
    int idx = tid + i * 256;
    int k = idx >> 6, d = idx & 63;
    wG[idx] = gcw[d * 64 + k];   // transposed: wG[k*64+d]
    wB[idx] = biw[d * 64 + k];
  }
  const int wv = tid >> 6, lane = tid & 63;
  const size_t row = (size_t)blockIdx.x * 4 + wv;
  const size_t off = row * DD + lane;
  const size_t P = (size_t)BB * NTOT * DD;
  float sv = sp[off] + sp[P + off] + sp[2 * P + off] + sp[3 * P + off];
  float ev = bf2f(ecat[row * KCAT + cin + lane]);
  rowS[wv][lane] = sv;
  rowE[wv][lane] = ev;
  __syncthreads();
  float sacc = gcb[lane];
  float bacc = bib[lane];
#pragma unroll 8
  for (int k = 0; k < 64; k++) {
    float sk = rowS[wv][k];
    float ek = rowE[wv][k];
    sacc += sk * wG[k * 64 + lane];
    bacc += (ek * sk) * wB[k * 64 + lane];
  }
  float s  = sacc > 0.f ? sacc : 0.01f * sacc;
  float bi = bacc > 0.f ? bacc : 0.01f * bacc;
  ecat[row * KCAT + cin + 64 + lane] = f2bf(s + bi);
}

// ---- scores = U @ I^T over K=192, bf16 MFMA, direct global frags ----
__global__ __launch_bounds__(256) void scores_mfma(
    const unsigned short* __restrict__ ecat, float* __restrict__ out) {
  const int tid = threadIdx.x;
  const int w = tid >> 6, l = tid & 63;
  const int lane15 = l & 15, quad = l >> 4;
  const int b = blockIdx.z;
  const int u0 = blockIdx.y * 64 + w * 16;
  const int i0 = blockIdx.x * 64;
  const unsigned short* U =
      ecat + ((size_t)b * NTOT + u0 + lane15) * KCAT + quad * 8;
  const unsigned short* I =
      ecat + ((size_t)b * NTOT + NUU + i0 + lane15) * KCAT + quad * 8;
  f32x4 acc[4];
#pragma unroll
  for (int t = 0; t < 4; t++) acc[t] = (f32x4){0.f, 0.f, 0.f, 0.f};
#pragma unroll
  for (int k = 0; k < KCAT; k += 32) {
    bf16x8 af = *reinterpret_cast<const bf16x8*>(U + k);
#pragma unroll
    for (int t = 0; t < 4; t++) {
      bf16x8 bf = *reinterpret_cast<const bf16x8*>(I + (size_t)t * 16 * KCAT + k);
      acc[t] = __builtin_amdgcn_mfma_f32_16x16x32_bf16(af, bf, acc[t], 0, 0, 0);
    }
  }
  float* O = out + (size_t)b * NUU * NII;
#pragma unroll
  for (int t = 0; t < 4; t++)
#pragma unroll
    for (int r = 0; r < 4; r++)
      O[(size_t)(u0 + quad * 4 + r) * NII + i0 + t * 16 + lane15] = acc[t][r];
}

// ---- in-place row log_softmax over 2048 ----
__global__ __launch_bounds__(256) void logsoftmax_kernel(float* __restrict__ out) {
  __shared__ float rm[4];
  __shared__ float rs[4];
  const int tid = threadIdx.x;
  const int lane = tid & 63, wv = tid >> 6;
  float* row = out + (size_t)blockIdx.x * NII;
  float4 v0 = *reinterpret_cast<const float4*>(row + tid * 4);
  float4 v1 = *reinterpret_cast<const float4*>(row + 1024 + tid * 4);
  float m = fmaxf(fmaxf(fmaxf(v0.x, v0.y), fmaxf(v0.z, v0.w)),
                  fmaxf(fmaxf(v1.x, v1.y), fmaxf(v1.z, v1.w)));
#pragma unroll
  for (int off = 32; off > 0; off >>= 1) m = fmaxf(m, __shfl_xor(m, off));
  if (lane == 0) rm[wv] = m;
  __syncthreads();
  m = fmaxf(fmaxf(rm[0], rm[1]), fmaxf(rm[2], rm[3]));
  float s = expf(v0.x - m) + expf(v0.y - m) + expf(v0.z - m) + expf(v0.w - m) +
            expf(v1.x - m) + expf(v1.y - m) + expf(v1.z - m) + expf(v1.w - m);
#pragma unroll
  for (int off = 32; off > 0; off >>= 1) s += __shfl_xor(s, off);
  if (lane == 0) rs[wv] = s;
  __syncthreads();
  float lse = m + logf(rs[0] + rs[1] + rs[2] + rs[3]);
  v0.x -= lse; v0.y -= lse; v0.z -= lse; v0.w -= lse;
  v1.x -= lse; v1.y -= lse; v1.z -= lse; v1.w -= lse;
  *reinterpret_cast<float4*>(row + tid * 4) = v0;
  *reinterpret_cast<float4*>(row + 1024 + tid * 4) = v1;
}

extern "C" void kernel_launch(void* const* d_in, const int* in_sizes, int n_in,
                              void* d_out, int out_size, void* d_ws, size_t ws_size,
                              hipStream_t stream) {
  (void)in_sizes; (void)n_in; (void)out_size; (void)ws_size;
  const int*   uidx = (const int*)d_in[0];
  const int*   iidx = (const int*)d_in[1];
  const float* adj  = (const float*)d_in[2];
  const float* utab = (const float*)d_in[3];
  const float* itab = (const float*)d_in[4];
  const float* gcw  = (const float*)d_in[5];
  const float* gcb  = (const float*)d_in[6];
  const float* biw  = (const float*)d_in[7];
  const float* bib  = (const float*)d_in[8];
  float* out = (float*)d_out;

  // ws: ecat bf16 [B][3072][192] (9.4MB) + Et bf16 [B][64][3072] (3.1MB)
  unsigned short* ecat = (unsigned short*)d_ws;
  unsigned short* Et   = ecat + (size_t)BB * NTOT * KCAT;
  // sp: 4 K-split fp32 partials [4][B][3072][64] = 25MB scratch inside d_out
  // (consumed by layer_post before scores_mfma overwrites d_out)
  float* sp = (float*)d_out;

  gather_bf16<<<dim3(BB * NTOT * 4 / 256), 256, 0, stream>>>(uidx, iidx, utab, itab, ecat);
  conv_t<<<dim3(48, BB), 256, 0, stream>>>(ecat, 0, Et);
  side_mfma<<<dim3(48, 4, BB), 256, 0, stream>>>(adj, Et, sp);
  layer_post<<<dim3(BB * NTOT / 4), 256, 0, stream>>>(sp, ecat, 0, gcw, gcb, biw, bib);
  conv_t<<<dim3(48, BB), 256, 0, stream>>>(ecat, 64, Et);
  side_mfma<<<dim3(48, 4, BB), 256, 0, stream>>>(adj, Et, sp);
  layer_post<<<dim3(BB * NTOT / 4), 256, 0, stream>>>(sp, ecat, 64, gcw + 4096, gcb + 64, biw + 4096, bib + 64);
  scores_mfma<<<dim3(32, 16, BB), 256, 0, stream>>>(ecat, out);
  logsoftmax_kernel<<<dim3(BB * NUU), 256, 0, stream>>>(out);
}